// Round 16
// baseline (335.894 us; speedup 1.0000x reference)
//
#include <hip/hip_runtime.h>

// ResidualNetwork forward, MI355X (gfx950).
// Round 16: minimal-intervention fix. r13 decomposition: ~1050 VALU instr/tile
// = 544 srcC zero-remat (16 movs x 34 MFMA; compiler re-emits the trivially-
// rematerializable zero vector per use) + 276 rc + staging/loop. r14/r15
// proved pinning WEIGHTS backfires (acc eviction -> accvgpr storm). So:
//  (a) pin ONLY the 16-reg zero srcC (opaque -> must stay resident, reused);
//  (b) rc forced to 4x v_pk_max_f32 + 4x v_cvt_pkrtz (8 instr, was 12);
//  (c) launch_bounds(256,4); weights left to the allocator exactly as r13.
// Chain unchanged from r13: 32x32x16_f16, sigma-permuted K axis (D dwords ARE
// next layer's B fragment), ones-row bias, ILP=2 tile chains.
// Budget/SIMD: VALU ~45-64k cyc (19-27us) | MFMA 4352 x ~8.5 = 37k (15us).

#define NPTS 4194304
#define NBLK 2048
#define NWAVES (NBLK * 4)           // 8192
#define NTILES (NPTS / 32)          // 131072
#define TPW (NTILES / NWAVES)       // 16 tiles per wave
#define NMM 34
#define ILP 2

typedef _Float16 h8 __attribute__((ext_vector_type(8)));
typedef float v8f __attribute__((ext_vector_type(8)));
typedef float v16f __attribute__((ext_vector_type(16)));
typedef unsigned u4v __attribute__((ext_vector_type(4)));

__device__ __forceinline__ v16f mm(h8 a, h8 b, v16f c) {
    return __builtin_amdgcn_mfma_f32_32x32x16_f16(a, b, c, 0, 0, 0);
}
__device__ __forceinline__ unsigned pkrtz(float a, float b) {
    return __builtin_bit_cast(unsigned, __builtin_amdgcn_cvt_pkrtz(a, b));
}
// relu + pack-cvt of the 8 live D regs (rows sigma(0..15) for this lane
// group); packed ops: 4x v_pk_max_f32 + 4x v_cvt_pkrtz = 8 VALU.
// Output IS the next layer's B fragment (sigma order).
__device__ __forceinline__ h8 rc(v16f d) {
    v8f lo8 = __builtin_shufflevector(d, d, 0, 1, 2, 3, 4, 5, 6, 7);
    v8f z8 = {0.f, 0.f, 0.f, 0.f, 0.f, 0.f, 0.f, 0.f};
    v8f m = __builtin_elementwise_max(lo8, z8);
    u4v u;
    u.x = pkrtz(m[0], m[1]);
    u.y = pkrtz(m[2], m[3]);
    u.z = pkrtz(m[4], m[5]);
    u.w = pkrtz(m[6], m[7]);
    return __builtin_bit_cast(h8, u);
}

// ---------------- prepack: A fragments, sigma-permuted K (one block per q) ---
__global__ __launch_bounds__(64) void prepack(
    const float* __restrict__ w0, const float* __restrict__ b0,
    const float* __restrict__ w1, const float* __restrict__ b1,
    const float* __restrict__ Wr1, const float* __restrict__ Br1,
    const float* __restrict__ Wr2, const float* __restrict__ Br2,
    const float* __restrict__ Wr3, const float* __restrict__ Br3,
    const float* __restrict__ w8, const float* __restrict__ b8,
    const float* __restrict__ w9, const float* __restrict__ b9,
    h8* __restrict__ tab)
{
    const int q = blockIdx.x, l = threadIdx.x;
    const int m = l & 31, g = l >> 5;
    h8 v;
#pragma unroll
    for (int j = 0; j < 8; ++j) {
        const int rr = (j & 3) + 8 * (j >> 2) + 4 * g;  // sigma(k)
        float a = 0.0f;
        if (q == 0) {
            if (m < 10 && rr < 3)        a = w0[rr * 10 + m];
            else if (m < 10 && rr == 3)  a = b0[m];
            else if (m == 10 && rr == 3) a = 1.0f;
        } else if (q == 33) {
            if (m == 0 && rr < 10)       a = w9[rr];
            else if (m == 0 && rr == 10) a = b9[0];
        } else {
            const float* W = nullptr;
            float bias = 0.0f;
            bool hasB = true, pass = true;
            if (q == 1)       { W = w1; bias = (m < 10) ? b1[m] : 0.0f; }
            else if (q == 32) { W = w8; bias = (m < 10) ? b8[m] : 0.0f; }
            else {
                const int qq = q - 2, bl = qq / 3, r = qq % 3;
                if (r == 0)      { W = Wr1 + bl * 100; bias = (m < 10) ? Br1[bl * 10 + m] : 0.0f; }
                else if (r == 1) { W = Wr2 + bl * 100; bias = (m < 10) ? Br2[bl * 10 + m] + Br3[bl * 10 + m] : 0.0f; }
                else             { W = Wr3 + bl * 100; hasB = false; pass = false; }
            }
            if (m < 10 && rr < 10)                a = W[rr * 10 + m];
            else if (m < 10 && rr == 10 && hasB)  a = bias;
            else if (m == 10 && rr == 10 && pass) a = 1.0f;
        }
        v[j] = (_Float16)a;
    }
    tab[q * 64 + l] = v;
}

// ---------------- main kernel: pinned zero srcC, rest left to allocator ------
__global__ __launch_bounds__(256, 4) void resnet_fwd(
    const float* __restrict__ x,
    const h8* __restrict__ tab,
    float* __restrict__ out)
{
    const int lane = threadIdx.x & 63;
    const int wv = blockIdx.x * 4 + (threadIdx.x >> 6);
    const int col = lane & 31;
    const bool lo = lane < 32;

    // weight fragments: loaded once per wave; allocator free to keep or remat
    h8 wA[NMM];
#pragma unroll
    for (int q = 0; q < NMM; ++q) wA[q] = tab[q * 64 + lane];

    // THE fix: one opaque zero srcC, resident in 16 VGPRs for the whole
    // kernel. Opaque => cannot be rematerialized per-MFMA (r13's 544
    // movs/tile), must be read as a register operand.
    v16f zero;
#pragma unroll
    for (int j = 0; j < 16; ++j) zero[j] = 0.0f;
    asm volatile("" : "+v"(zero));

    const long tile0 = (long)wv * TPW;

    for (int t = 0; t < TPW; t += ILP) {
        long base[ILP];
        h8 hh[ILP];

        // layer-0 B: lanes 0-31 carry (x0,x1,x2,1) in k-rows 0-3; rest zero
#pragma unroll
        for (int c = 0; c < ILP; ++c) {
            base[c] = (tile0 + t + c) * 32;
            float a0 = 0.f, a1 = 0.f, a2 = 0.f, a3 = 0.f;
            if (lo) {
                const float* p = x + (base[c] + col) * 3;
                a0 = p[0]; a1 = p[1]; a2 = p[2]; a3 = 1.0f;
            }
            u4v u;
            u.x = pkrtz(a0, a1);
            u.y = pkrtz(a2, a3);
            u.z = 0u; u.w = 0u;
            hh[c] = __builtin_bit_cast(h8, u);
        }

        // layer 0, layer 1
#pragma unroll
        for (int c = 0; c < ILP; ++c) hh[c] = rc(mm(wA[0], hh[c], zero));
#pragma unroll
        for (int c = 0; c < ILP; ++c) hh[c] = rc(mm(wA[1], hh[c], zero));

        // residual blocks; accumulator liveness capped (d1 dies before d2)
#pragma unroll
        for (int bl = 0; bl < 10; ++bl) {
            h8 t1[ILP];
            {
                v16f d1[ILP];
#pragma unroll
                for (int c = 0; c < ILP; ++c) d1[c] = mm(wA[2 + 3 * bl], hh[c], zero);
#pragma unroll
                for (int c = 0; c < ILP; ++c) t1[c] = rc(d1[c]);
            }
            {
                v16f d2[ILP];
#pragma unroll
                for (int c = 0; c < ILP; ++c) d2[c] = mm(wA[3 + 3 * bl], hh[c], zero);
#pragma unroll
                for (int c = 0; c < ILP; ++c) d2[c] = mm(wA[4 + 3 * bl], t1[c], d2[c]);
#pragma unroll
                for (int c = 0; c < ILP; ++c) hh[c] = rc(d2[c]);
            }
        }

        // layer 8
#pragma unroll
        for (int c = 0; c < ILP; ++c) hh[c] = rc(mm(wA[32], hh[c], zero));

        // output layer: D row 0 (lanes 0-31, reg 0) = result for 32 points
#pragma unroll
        for (int c = 0; c < ILP; ++c) {
            v16f d = mm(wA[33], hh[c], zero);
            if (lo) out[base[c] + col] = d[0];
        }
    }
}

extern "C" void kernel_launch(void* const* d_in, const int* in_sizes, int n_in,
                              void* d_out, int out_size, void* d_ws, size_t ws_size,
                              hipStream_t stream)
{
    const float* x   = (const float*)d_in[0];
    const float* w0  = (const float*)d_in[1];
    const float* b0  = (const float*)d_in[2];
    const float* w1  = (const float*)d_in[3];
    const float* b1  = (const float*)d_in[4];
    const float* Wr1 = (const float*)d_in[5];
    const float* Br1 = (const float*)d_in[6];
    const float* Wr2 = (const float*)d_in[7];
    const float* Br2 = (const float*)d_in[8];
    const float* Wr3 = (const float*)d_in[9];
    const float* Br3 = (const float*)d_in[10];
    const float* w8  = (const float*)d_in[11];
    const float* b8  = (const float*)d_in[12];
    const float* w9  = (const float*)d_in[13];
    const float* b9  = (const float*)d_in[14];
    float* out = (float*)d_out;
    h8* tab = (h8*)d_ws;   // 34 * 64 * 16B = 34.8 KB scratch

    hipLaunchKernelGGL(prepack, dim3(NMM), dim3(64), 0, stream,
                       w0, b0, w1, b1, Wr1, Br1, Wr2, Br2, Wr3, Br3,
                       w8, b8, w9, b9, tab);

    hipLaunchKernelGGL(resnet_fwd, dim3(NBLK), dim3(256), 0, stream,
                       x, (const h8*)tab, out);
}

// Round 17
// 241.206 us; speedup vs baseline: 1.3926x; 1.3926x over previous
//
#include <hip/hip_runtime.h>

// ResidualNetwork forward, MI355X (gfx950).
// Round 17: THE controlled experiment r16 was meant to be. r16 accidentally
// quartered the VGPR budget ((256,4) -> VGPR 64) causing true scratch spill
// (FETCH 650MB, WRITE 180MB). Allocator map: (256,2) no pins = L1 remat
// (r13, 162us); (256,1)+pins = accvgpr storm (r14/15); (256,4) = spill (r16).
// Untested cell: (256,2) + pinned zero srcC ONLY. r13 decomposition says
// 544 of ~1060 VALU instr/tile are 16-reg zero re-materialization per MFMA;
// the pin makes srcC a plain register read.
// Chain identical to r13: 32x32x16_f16, sigma-permuted K (D dwords ARE next
// B fragment), ones-row bias, ILP=2, launch_bounds(256,2), no weight pins.
// Budget/SIMD: VALU ~132k cyc (55us) | MFMA 128x34x8.5 = 37k (15us).
// Gates: FETCH ~24.8MB, WRITE 16.4MB (no spill); VALUBusy 55-65%; Mfma 45+%.

#define NPTS 4194304
#define NBLK 2048
#define NWAVES (NBLK * 4)           // 8192
#define NTILES (NPTS / 32)          // 131072
#define TPW (NTILES / NWAVES)       // 16 tiles per wave
#define NMM 34
#define ILP 2

typedef _Float16 h8 __attribute__((ext_vector_type(8)));
typedef float v8f __attribute__((ext_vector_type(8)));
typedef float v16f __attribute__((ext_vector_type(16)));
typedef unsigned u4v __attribute__((ext_vector_type(4)));

__device__ __forceinline__ v16f mm(h8 a, h8 b, v16f c) {
    return __builtin_amdgcn_mfma_f32_32x32x16_f16(a, b, c, 0, 0, 0);
}
__device__ __forceinline__ unsigned pkrtz(float a, float b) {
    return __builtin_bit_cast(unsigned, __builtin_amdgcn_cvt_pkrtz(a, b));
}
// relu + pack-cvt of the 8 live D regs; output IS next layer's B (sigma order)
__device__ __forceinline__ h8 rc(v16f d) {
    v8f lo8 = __builtin_shufflevector(d, d, 0, 1, 2, 3, 4, 5, 6, 7);
    v8f z8 = {0.f, 0.f, 0.f, 0.f, 0.f, 0.f, 0.f, 0.f};
    v8f m = __builtin_elementwise_max(lo8, z8);
    u4v u;
    u.x = pkrtz(m[0], m[1]);
    u.y = pkrtz(m[2], m[3]);
    u.z = pkrtz(m[4], m[5]);
    u.w = pkrtz(m[6], m[7]);
    return __builtin_bit_cast(h8, u);
}

// ---------------- prepack: A fragments, sigma-permuted K (one block per q) ---
__global__ __launch_bounds__(64) void prepack(
    const float* __restrict__ w0, const float* __restrict__ b0,
    const float* __restrict__ w1, const float* __restrict__ b1,
    const float* __restrict__ Wr1, const float* __restrict__ Br1,
    const float* __restrict__ Wr2, const float* __restrict__ Br2,
    const float* __restrict__ Wr3, const float* __restrict__ Br3,
    const float* __restrict__ w8, const float* __restrict__ b8,
    const float* __restrict__ w9, const float* __restrict__ b9,
    h8* __restrict__ tab)
{
    const int q = blockIdx.x, l = threadIdx.x;
    const int m = l & 31, g = l >> 5;
    h8 v;
#pragma unroll
    for (int j = 0; j < 8; ++j) {
        const int rr = (j & 3) + 8 * (j >> 2) + 4 * g;  // sigma(k)
        float a = 0.0f;
        if (q == 0) {
            if (m < 10 && rr < 3)        a = w0[rr * 10 + m];
            else if (m < 10 && rr == 3)  a = b0[m];
            else if (m == 10 && rr == 3) a = 1.0f;
        } else if (q == 33) {
            if (m == 0 && rr < 10)       a = w9[rr];
            else if (m == 0 && rr == 10) a = b9[0];
        } else {
            const float* W = nullptr;
            float bias = 0.0f;
            bool hasB = true, pass = true;
            if (q == 1)       { W = w1; bias = (m < 10) ? b1[m] : 0.0f; }
            else if (q == 32) { W = w8; bias = (m < 10) ? b8[m] : 0.0f; }
            else {
                const int qq = q - 2, bl = qq / 3, r = qq % 3;
                if (r == 0)      { W = Wr1 + bl * 100; bias = (m < 10) ? Br1[bl * 10 + m] : 0.0f; }
                else if (r == 1) { W = Wr2 + bl * 100; bias = (m < 10) ? Br2[bl * 10 + m] + Br3[bl * 10 + m] : 0.0f; }
                else             { W = Wr3 + bl * 100; hasB = false; pass = false; }
            }
            if (m < 10 && rr < 10)                a = W[rr * 10 + m];
            else if (m < 10 && rr == 10 && hasB)  a = bias;
            else if (m == 10 && rr == 10 && pass) a = 1.0f;
        }
        v[j] = (_Float16)a;
    }
    tab[q * 64 + l] = v;
}

// ---------------- main kernel: r13 config + pinned zero srcC -----------------
__global__ __launch_bounds__(256, 2) void resnet_fwd(
    const float* __restrict__ x,
    const h8* __restrict__ tab,
    float* __restrict__ out)
{
    const int lane = threadIdx.x & 63;
    const int wv = blockIdx.x * 4 + (threadIdx.x >> 6);
    const int col = lane & 31;
    const bool lo = lane < 32;

    // weight fragments: loaded once; allocator free to keep or remat (as r13)
    h8 wA[NMM];
#pragma unroll
    for (int q = 0; q < NMM; ++q) wA[q] = tab[q * 64 + lane];

    // the single intervention: opaque zero srcC, resident in 16 VGPRs,
    // read as a register operand by all 34 MFMAs (kills 544 movs/tile).
    v16f zero;
#pragma unroll
    for (int j = 0; j < 16; ++j) zero[j] = 0.0f;
    asm volatile("" : "+v"(zero));

    const long tile0 = (long)wv * TPW;

    for (int t = 0; t < TPW; t += ILP) {
        long base[ILP];
        h8 hh[ILP];

        // layer-0 B: lanes 0-31 carry (x0,x1,x2,1) in k-rows 0-3; rest zero
#pragma unroll
        for (int c = 0; c < ILP; ++c) {
            base[c] = (tile0 + t + c) * 32;
            float a0 = 0.f, a1 = 0.f, a2 = 0.f, a3 = 0.f;
            if (lo) {
                const float* p = x + (base[c] + col) * 3;
                a0 = p[0]; a1 = p[1]; a2 = p[2]; a3 = 1.0f;
            }
            u4v u;
            u.x = pkrtz(a0, a1);
            u.y = pkrtz(a2, a3);
            u.z = 0u; u.w = 0u;
            hh[c] = __builtin_bit_cast(h8, u);
        }

        // layer 0, layer 1
#pragma unroll
        for (int c = 0; c < ILP; ++c) hh[c] = rc(mm(wA[0], hh[c], zero));
#pragma unroll
        for (int c = 0; c < ILP; ++c) hh[c] = rc(mm(wA[1], hh[c], zero));

        // residual blocks; accumulator liveness capped (d1 dies before d2)
#pragma unroll
        for (int bl = 0; bl < 10; ++bl) {
            h8 t1[ILP];
            {
                v16f d1[ILP];
#pragma unroll
                for (int c = 0; c < ILP; ++c) d1[c] = mm(wA[2 + 3 * bl], hh[c], zero);
#pragma unroll
                for (int c = 0; c < ILP; ++c) t1[c] = rc(d1[c]);
            }
            {
                v16f d2[ILP];
#pragma unroll
                for (int c = 0; c < ILP; ++c) d2[c] = mm(wA[3 + 3 * bl], hh[c], zero);
#pragma unroll
                for (int c = 0; c < ILP; ++c) d2[c] = mm(wA[4 + 3 * bl], t1[c], d2[c]);
#pragma unroll
                for (int c = 0; c < ILP; ++c) hh[c] = rc(d2[c]);
            }
        }

        // layer 8
#pragma unroll
        for (int c = 0; c < ILP; ++c) hh[c] = rc(mm(wA[32], hh[c], zero));

        // output layer: D row 0 (lanes 0-31, reg 0) = result for 32 points
#pragma unroll
        for (int c = 0; c < ILP; ++c) {
            v16f d = mm(wA[33], hh[c], zero);
            if (lo) out[base[c] + col] = d[0];
        }
    }
}

extern "C" void kernel_launch(void* const* d_in, const int* in_sizes, int n_in,
                              void* d_out, int out_size, void* d_ws, size_t ws_size,
                              hipStream_t stream)
{
    const float* x   = (const float*)d_in[0];
    const float* w0  = (const float*)d_in[1];
    const float* b0  = (const float*)d_in[2];
    const float* w1  = (const float*)d_in[3];
    const float* b1  = (const float*)d_in[4];
    const float* Wr1 = (const float*)d_in[5];
    const float* Br1 = (const float*)d_in[6];
    const float* Wr2 = (const float*)d_in[7];
    const float* Br2 = (const float*)d_in[8];
    const float* Wr3 = (const float*)d_in[9];
    const float* Br3 = (const float*)d_in[10];
    const float* w8  = (const float*)d_in[11];
    const float* b8  = (const float*)d_in[12];
    const float* w9  = (const float*)d_in[13];
    const float* b9  = (const float*)d_in[14];
    float* out = (float*)d_out;
    h8* tab = (h8*)d_ws;   // 34 * 64 * 16B = 34.8 KB scratch

    hipLaunchKernelGGL(prepack, dim3(NMM), dim3(64), 0, stream,
                       w0, b0, w1, b1, Wr1, Br1, Wr2, Br2, Wr3, Br3,
                       w8, b8, w9, b9, tab);

    hipLaunchKernelGGL(resnet_fwd, dim3(NBLK), dim3(256), 0, stream,
                       x, (const h8*)tab, out);
}